// Round 1
// baseline (261.968 us; speedup 1.0000x reference)
//
#include <hip/hip_runtime.h>

#define NROWS 2048
#define D 64
#define HSTR 68   // LDS row stride: 68 floats = 272 B, 16B-aligned, bank-offset 4 per row

// ---------------- Kernel A: per-row precompute ----------------
// e[n]  = concat(subj_t[si], rel_t[ri], obj_t[oi]) @ proj_w.T + proj_b   (64)
// hi[n] = e[n] @ w1[:, :64].T + b1      (b1 folded here)
// hj[n] = e[n] @ w1[:, 64:].T
__global__ __launch_bounds__(256) void precompute_kernel(
    const int* __restrict__ subj_idx, const int* __restrict__ rel_idx,
    const int* __restrict__ obj_idx,
    const float* __restrict__ subj_table, const float* __restrict__ rel_table,
    const float* __restrict__ obj_table,
    const float* __restrict__ proj_w, const float* __restrict__ proj_b,
    const float* __restrict__ w1, const float* __restrict__ b1,
    float* __restrict__ hi_out, float* __restrict__ hj_out)
{
    __shared__ float comb[4][192];
    __shared__ float e_s[4][64];
    const int d = threadIdx.x;          // 0..63
    const int g = threadIdx.y;          // 0..3
    const int n = blockIdx.x * 4 + g;

    const int si = subj_idx[n];
    const int ri = rel_idx[n];
    const int oi = obj_idx[n];
    comb[g][d]       = subj_table[si * 64 + d];
    comb[g][64 + d]  = rel_table[ri * 64 + d];
    comb[g][128 + d] = obj_table[oi * 64 + d];
    __syncthreads();

    float acc = proj_b[d];
    #pragma unroll
    for (int c = 0; c < 192; ++c)
        acc = fmaf(comb[g][c], proj_w[d * 192 + c], acc);
    e_s[g][d] = acc;
    __syncthreads();

    float hi = b1[d];
    float hj = 0.f;
    #pragma unroll
    for (int k = 0; k < 64; ++k) {
        const float ek = e_s[g][k];
        hi = fmaf(ek, w1[d * 128 + k], hi);
        hj = fmaf(ek, w1[d * 128 + 64 + k], hj);
    }
    hi_out[n * 64 + d] = hi;
    hj_out[n * 64 + d] = hj;
}

// ---------------- Kernel B: pairwise scores ----------------
// For pair (i,j): h = relu(hi[i]+hj[j]); h2 = relu(h @ w2.T + b2);
// out[i][j] = (j>i) ? sigmoid(h2.w3 + b3) : 0
__global__ __launch_bounds__(256) void pair_kernel(
    const float* __restrict__ hi_ws, const float* __restrict__ hj_ws,
    const float* __restrict__ w2, const float* __restrict__ b2,
    const float* __restrict__ w3, const float* __restrict__ b3,
    float* __restrict__ out)
{
    const int jj = threadIdx.x;         // 0..15
    const int ii = threadIdx.y;         // 0..15
    const int i0 = blockIdx.y * 16;
    const int j0 = blockIdx.x * 16;
    const int i = i0 + ii;
    const int j = j0 + jj;

    // Entire tile at/below diagonal -> zeros (output is poisoned, must write).
    if (j0 + 15 <= i0) {
        out[i * NROWS + j] = 0.f;
        return;
    }

    __shared__ float hiT[16 * HSTR];
    __shared__ float hjT[16 * HSTR];
    const int tid = ii * 16 + jj;
    for (int idx = tid; idx < 16 * 64; idx += 256) {
        const int r = idx >> 6;
        const int c = idx & 63;
        hiT[r * HSTR + c] = hi_ws[(i0 + r) * 64 + c];
        hjT[r * HSTR + c] = hj_ws[(j0 + r) * 64 + c];
    }
    __syncthreads();

    float acc[32];
    #pragma unroll
    for (int k = 0; k < 32; ++k) acc[k] = b2[k];   // uniform -> s_load

    #pragma unroll
    for (int d = 0; d < 64; ++d) {
        float hd = hiT[ii * HSTR + d] + hjT[jj * HSTR + d];
        hd = fmaxf(hd, 0.f);
        #pragma unroll
        for (int k = 0; k < 32; ++k)
            acc[k] = fmaf(hd, w2[k * 64 + d], acc[k]);  // w2 uniform -> SGPR operand
    }

    float s = b3[0];
    #pragma unroll
    for (int k = 0; k < 32; ++k)
        s = fmaf(fmaxf(acc[k], 0.f), w3[k], s);

    const float score = 1.f / (1.f + __expf(-s));
    out[i * NROWS + j] = (j > i) ? score : 0.f;
}

extern "C" void kernel_launch(void* const* d_in, const int* in_sizes, int n_in,
                              void* d_out, int out_size, void* d_ws, size_t ws_size,
                              hipStream_t stream) {
    const int*   subj_idx   = (const int*)d_in[0];
    const int*   rel_idx    = (const int*)d_in[1];
    const int*   obj_idx    = (const int*)d_in[2];
    const float* subj_table = (const float*)d_in[3];
    const float* rel_table  = (const float*)d_in[4];
    const float* obj_table  = (const float*)d_in[5];
    const float* proj_w     = (const float*)d_in[6];
    const float* proj_b     = (const float*)d_in[7];
    const float* w1         = (const float*)d_in[8];
    const float* b1         = (const float*)d_in[9];
    const float* w2         = (const float*)d_in[10];
    const float* b2         = (const float*)d_in[11];
    const float* w3         = (const float*)d_in[12];
    const float* b3         = (const float*)d_in[13];
    float* out = (float*)d_out;

    float* hi_ws = (float*)d_ws;                 // N*64 floats
    float* hj_ws = hi_ws + NROWS * 64;           // N*64 floats (1 MB total)

    precompute_kernel<<<dim3(NROWS / 4), dim3(64, 4), 0, stream>>>(
        subj_idx, rel_idx, obj_idx, subj_table, rel_table, obj_table,
        proj_w, proj_b, w1, b1, hi_ws, hj_ws);

    pair_kernel<<<dim3(NROWS / 16, NROWS / 16), dim3(16, 16), 0, stream>>>(
        hi_ws, hj_ws, w2, b2, w3, b3, out);
}

// Round 2
// 222.071 us; speedup vs baseline: 1.1797x; 1.1797x over previous
//
#include <hip/hip_runtime.h>
#include <hip/hip_bf16.h>

#define NROWS 2048

typedef __attribute__((ext_vector_type(8))) short bf16x8;   // 8 bf16 in 4 VGPRs
typedef __attribute__((ext_vector_type(4))) short bf16x4;   // 4 bf16, 8B (b64-aligned LDS ops)
typedef __attribute__((ext_vector_type(4))) float f32x4;

// fp32 -> bf16 bits, round-to-nearest-even
static __device__ __forceinline__ short f2bf(float f) {
    union { float f; unsigned u; } v; v.f = f;
    unsigned r = (v.u + 0x7fffu + ((v.u >> 16) & 1u)) >> 16;
    return (short)r;
}

// ---------------- Kernel A: per-row precompute ----------------
// Weights staged in padded LDS (uniform-row access was the old kernel's VMEM sink).
// 4 rows per block, one row per wave; lane d owns output dim d.
__global__ __launch_bounds__(256) void precompute_kernel(
    const int* __restrict__ subj_idx, const int* __restrict__ rel_idx,
    const int* __restrict__ obj_idx,
    const float* __restrict__ subj_table, const float* __restrict__ rel_table,
    const float* __restrict__ obj_table,
    const float* __restrict__ proj_w, const float* __restrict__ proj_b,
    const float* __restrict__ w1, const float* __restrict__ b1,
    float* __restrict__ hi_out, float* __restrict__ hj_out)
{
    __shared__ float wbuf[64 * 193];   // proj_w padded (stride 193 -> bank (d+c)%32), reused for w1 (stride 129)
    __shared__ float comb[4 * 192];
    __shared__ float e_s[4 * 64];

    const int tid = threadIdx.x;
    const int d = tid & 63;            // output dim
    const int g = tid >> 6;            // wave id == local row
    const int n0 = blockIdx.x * 4;
    const int n = n0 + g;

    // gather combined embedding (row-uniform indices -> s_load)
    comb[g * 192 +       d] = subj_table[subj_idx[n] * 64 + d];
    comb[g * 192 +  64 + d] = rel_table [rel_idx [n] * 64 + d];
    comb[g * 192 + 128 + d] = obj_table [obj_idx [n] * 64 + d];

    // stage proj_w (64x192) padded: thread t copies 48 floats of row t>>2
    {
        const int r = tid >> 2, c0 = (tid & 3) * 48;
        #pragma unroll 8
        for (int j = 0; j < 48; ++j)
            wbuf[r * 193 + c0 + j] = proj_w[r * 192 + c0 + j];
    }
    __syncthreads();

    float acc = proj_b[d];
    #pragma unroll 8
    for (int c = 0; c < 192; ++c)
        acc = fmaf(comb[g * 192 + c], wbuf[d * 193 + c], acc);
    e_s[g * 64 + d] = acc;
    __syncthreads();   // phase A fully done before wbuf is restaged

    // restage with w1 (64x128), stride 129
    {
        const int r = tid >> 2, c0 = (tid & 3) * 32;
        #pragma unroll 8
        for (int j = 0; j < 32; ++j)
            wbuf[r * 129 + c0 + j] = w1[r * 128 + c0 + j];
    }
    __syncthreads();

    float hi = b1[d];
    float hj = 0.f;
    #pragma unroll 8
    for (int k = 0; k < 64; ++k) {
        const float ek = e_s[g * 64 + k];          // wave-uniform broadcast
        hi = fmaf(ek, wbuf[d * 129 + k], hi);
        hj = fmaf(ek, wbuf[d * 129 + 64 + k], hj);
    }
    hi_out[n * 64 + d] = hi;
    hj_out[n * 64 + d] = hj;
}

// ---------------- Kernel B: pairwise scores via MFMA ----------------
// Per block: 16x16 pair tile. h(256x64) = relu(hi[ii]+hj[jj]) -> bf16 LDS.
// GEMM h @ w2^T (M=256,N=32,K=64) with mfma_f32_16x16x32_bf16 (4 M-tiles/wave,
// 2 N-tiles, 2 K-steps). Epilogue: relu(+b2), dot w3 via 16-lane shuffle
// butterfly, sigmoid, masked store.
#define HS_STRIDE 76   // shorts per h-row: 152 B, 8B-aligned, breaks pow2 banking

__global__ __launch_bounds__(256) void pair_kernel(
    const float* __restrict__ hi_ws, const float* __restrict__ hj_ws,
    const float* __restrict__ w2, const float* __restrict__ b2,
    const float* __restrict__ w3, const float* __restrict__ b3,
    float* __restrict__ out)
{
    const int tid = threadIdx.x;
    const int i0 = blockIdx.y * 16;
    const int j0 = blockIdx.x * 16;

    // strictly-below-diagonal block: write zeros (out is poisoned) and exit
    if (blockIdx.x < blockIdx.y) {
        out[(i0 + (tid >> 4)) * NROWS + (j0 + (tid & 15))] = 0.f;
        return;
    }

    __shared__ short hs[256 * HS_STRIDE];   // 38912 B

    const int lane = tid & 63;
    const int wid  = tid >> 6;
    const int col  = lane & 15;
    const int quad = lane >> 4;

    // B fragments (block-invariant): B[k][n] = w2[n][k]; lane holds n=col,
    // k = ks*32 + quad*8 + j  -> 8 contiguous floats of w2 row n.
    bf16x8 bfrag[2][2];
    #pragma unroll
    for (int nt = 0; nt < 2; ++nt) {
        #pragma unroll
        for (int ks = 0; ks < 2; ++ks) {
            const float* wr = w2 + (nt * 16 + col) * 64 + ks * 32 + quad * 8;
            bf16x8 f;
            #pragma unroll
            for (int j = 0; j < 8; ++j) f[j] = f2bf(wr[j]);
            bfrag[nt][ks] = f;
        }
    }
    const float b2c0 = b2[col], b2c1 = b2[col + 16];
    const float w3c0 = w3[col], w3c1 = w3[col + 16];
    const float b3v  = b3[0];

    // h tile: thread owns pair p=tid; 64 dims as 16 float4 pairs -> bf16 LDS
    {
        const int p = tid, ii = p >> 4, jj = p & 15;
        const float4* hi4 = (const float4*)(hi_ws + (size_t)(i0 + ii) * 64);
        const float4* hj4 = (const float4*)(hj_ws + (size_t)(j0 + jj) * 64);
        #pragma unroll
        for (int c = 0; c < 16; ++c) {
            const float4 a = hi4[c];
            const float4 b = hj4[c];
            bf16x4 s;
            s[0] = f2bf(fmaxf(a.x + b.x, 0.f));
            s[1] = f2bf(fmaxf(a.y + b.y, 0.f));
            s[2] = f2bf(fmaxf(a.z + b.z, 0.f));
            s[3] = f2bf(fmaxf(a.w + b.w, 0.f));
            *(bf16x4*)&hs[p * HS_STRIDE + c * 4] = s;
        }
    }
    __syncthreads();

    #pragma unroll
    for (int t = 0; t < 4; ++t) {
        const int mt = wid * 4 + t;                      // M-tile == local row ii
        const short* arow = &hs[(mt * 16 + col) * HS_STRIDE + quad * 8];

        // A fragments: lane holds A[m=col][k=ks*32+quad*8+j]
        bf16x8 a0, a1;
        {
            const bf16x4 l0 = *(const bf16x4*)(arow);
            const bf16x4 h0 = *(const bf16x4*)(arow + 4);
            const bf16x4 l1 = *(const bf16x4*)(arow + 32);
            const bf16x4 h1 = *(const bf16x4*)(arow + 36);
            a0[0]=l0[0]; a0[1]=l0[1]; a0[2]=l0[2]; a0[3]=l0[3];
            a0[4]=h0[0]; a0[5]=h0[1]; a0[6]=h0[2]; a0[7]=h0[3];
            a1[0]=l1[0]; a1[1]=l1[1]; a1[2]=l1[2]; a1[3]=l1[3];
            a1[4]=h1[0]; a1[5]=h1[1]; a1[6]=h1[2]; a1[7]=h1[3];
        }

        f32x4 acc0 = {0.f, 0.f, 0.f, 0.f};
        f32x4 acc1 = {0.f, 0.f, 0.f, 0.f};
        acc0 = __builtin_amdgcn_mfma_f32_16x16x32_bf16(a0, bfrag[0][0], acc0, 0, 0, 0);
        acc0 = __builtin_amdgcn_mfma_f32_16x16x32_bf16(a1, bfrag[0][1], acc0, 0, 0, 0);
        acc1 = __builtin_amdgcn_mfma_f32_16x16x32_bf16(a0, bfrag[1][0], acc1, 0, 0, 0);
        acc1 = __builtin_amdgcn_mfma_f32_16x16x32_bf16(a1, bfrag[1][1], acc1, 0, 0, 0);

        // epilogue: lane holds D[row=quad*4+r][n=col] (+ col+16 in acc1)
        float part0 = fmaxf(acc0[0] + b2c0, 0.f) * w3c0 + fmaxf(acc1[0] + b2c1, 0.f) * w3c1;
        float part1 = fmaxf(acc0[1] + b2c0, 0.f) * w3c0 + fmaxf(acc1[1] + b2c1, 0.f) * w3c1;
        float part2 = fmaxf(acc0[2] + b2c0, 0.f) * w3c0 + fmaxf(acc1[2] + b2c1, 0.f) * w3c1;
        float part3 = fmaxf(acc0[3] + b2c0, 0.f) * w3c0 + fmaxf(acc1[3] + b2c1, 0.f) * w3c1;

        // butterfly over the 4 col bits: sum across 16 lanes of each quad
        #pragma unroll
        for (int m = 1; m <= 8; m <<= 1) {
            part0 += __shfl_xor(part0, m);
            part1 += __shfl_xor(part1, m);
            part2 += __shfl_xor(part2, m);
            part3 += __shfl_xor(part3, m);
        }

        if (col < 4) {
            const float sv = (col & 1) ? ((col & 2) ? part3 : part1)
                                       : ((col & 2) ? part2 : part0);
            const int i = i0 + mt;
            const int j = j0 + quad * 4 + col;   // row within M-tile = jj
            const float score = 1.f / (1.f + __expf(-(sv + b3v)));
            out[i * NROWS + j] = (j > i) ? score : 0.f;
        }
    }
}

extern "C" void kernel_launch(void* const* d_in, const int* in_sizes, int n_in,
                              void* d_out, int out_size, void* d_ws, size_t ws_size,
                              hipStream_t stream) {
    const int*   subj_idx   = (const int*)d_in[0];
    const int*   rel_idx    = (const int*)d_in[1];
    const int*   obj_idx    = (const int*)d_in[2];
    const float* subj_table = (const float*)d_in[3];
    const float* rel_table  = (const float*)d_in[4];
    const float* obj_table  = (const float*)d_in[5];
    const float* proj_w     = (const float*)d_in[6];
    const float* proj_b     = (const float*)d_in[7];
    const float* w1         = (const float*)d_in[8];
    const float* b1         = (const float*)d_in[9];
    const float* w2         = (const float*)d_in[10];
    const float* b2         = (const float*)d_in[11];
    const float* w3         = (const float*)d_in[12];
    const float* b3         = (const float*)d_in[13];
    float* out = (float*)d_out;

    float* hi_ws = (float*)d_ws;                 // N*64 floats
    float* hj_ws = hi_ws + NROWS * 64;           // N*64 floats (1 MB total)

    precompute_kernel<<<dim3(NROWS / 4), dim3(256), 0, stream>>>(
        subj_idx, rel_idx, obj_idx, subj_table, rel_table, obj_table,
        proj_w, proj_b, w1, b1, hi_ws, hj_ws);

    pair_kernel<<<dim3(NROWS / 16, NROWS / 16), dim3(256), 0, stream>>>(
        hi_ws, hj_ws, w2, b2, w3, b3, out);
}

// Round 3
// 147.348 us; speedup vs baseline: 1.7779x; 1.5071x over previous
//
#include <hip/hip_runtime.h>
#include <hip/hip_bf16.h>

#define NROWS 2048
#define HST 68   // LDS row stride in floats: 272 B, 16B-aligned

typedef __attribute__((ext_vector_type(8))) short bf16x8;
typedef __attribute__((ext_vector_type(4))) float f32x4;

union Frag { bf16x8 v; unsigned u[4]; };

// pack two fp32 -> packed bf16 pair (hopes for v_cvt_pk_bf16_f32)
static __device__ __forceinline__ unsigned cvt2(float a, float b) {
    __hip_bfloat162 h = __float22bfloat162_rn(float2{a, b});
    union { __hip_bfloat162 h2; unsigned u; } c; c.h2 = h; return c.u;
}

// ---------------- Kernel A: per-row precompute ----------------
// One wave per row; lane d owns output dim d. Weights read from global
// (proj_w 48KB / w1 32KB are L1/L2-resident and reused by all blocks).
__global__ __launch_bounds__(256) void precompute_kernel(
    const int* __restrict__ subj_idx, const int* __restrict__ rel_idx,
    const int* __restrict__ obj_idx,
    const float* __restrict__ subj_table, const float* __restrict__ rel_table,
    const float* __restrict__ obj_table,
    const float* __restrict__ proj_w, const float* __restrict__ proj_b,
    const float* __restrict__ w1, const float* __restrict__ b1,
    float* __restrict__ hi_out, float* __restrict__ hj_out)
{
    __shared__ float e_s[4 * 64];
    const int lane = threadIdx.x & 63;
    const int g = threadIdx.x >> 6;
    const int n = blockIdx.x * 4 + g;
    const int d = lane;

    const float4* sr = (const float4*)(subj_table + subj_idx[n] * 64);
    const float4* rr = (const float4*)(rel_table + rel_idx[n] * 64);
    const float4* orw = (const float4*)(obj_table + obj_idx[n] * 64);
    const float4* pw = (const float4*)(proj_w + d * 192);

    float acc = proj_b[d];
    #pragma unroll
    for (int c = 0; c < 16; ++c) {
        const float4 wv = pw[c], cv = sr[c];
        acc += cv.x * wv.x + cv.y * wv.y + cv.z * wv.z + cv.w * wv.w;
    }
    #pragma unroll
    for (int c = 0; c < 16; ++c) {
        const float4 wv = pw[16 + c], cv = rr[c];
        acc += cv.x * wv.x + cv.y * wv.y + cv.z * wv.z + cv.w * wv.w;
    }
    #pragma unroll
    for (int c = 0; c < 16; ++c) {
        const float4 wv = pw[32 + c], cv = orw[c];
        acc += cv.x * wv.x + cv.y * wv.y + cv.z * wv.z + cv.w * wv.w;
    }
    e_s[g * 64 + d] = acc;
    __syncthreads();

    float hi = b1[d], hj = 0.f;
    const float4* ev = (const float4*)(e_s + g * 64);
    const float4* wr = (const float4*)(w1 + d * 128);
    #pragma unroll
    for (int k = 0; k < 16; ++k) {
        const float4 e4 = ev[k], wa = wr[k], wb = wr[16 + k];
        hi += e4.x * wa.x + e4.y * wa.y + e4.z * wa.z + e4.w * wa.w;
        hj += e4.x * wb.x + e4.y * wb.y + e4.z * wb.z + e4.w * wb.w;
    }
    hi_out[n * 64 + d] = hi;
    hj_out[n * 64 + d] = hj;
}

// ---------------- Kernel B: pairwise scores via MFMA ----------------
// 32x32 pair tile / block (4 waves). Wave (wi,wj): i-half wi*16.., j-group
// wj*16+col. D = w2_tile(A, m=channel) x h(B, n=pair): channel dim lands in
// registers -> w3-dot is 8 in-register fma + 2 cross-lane shuffles.
__global__ __launch_bounds__(256, 4) void pair_kernel(
    const float* __restrict__ hi_ws, const float* __restrict__ hj_ws,
    const float* __restrict__ w2, const float* __restrict__ b2,
    const float* __restrict__ w3, const float* __restrict__ b3,
    float* __restrict__ out)
{
    const int bx = blockIdx.x, by = blockIdx.y;
    const int i0 = by * 32, j0 = bx * 32;
    const int tid = threadIdx.x;

    if (bx < by) {   // entire tile strictly below diagonal -> zeros
        const float4 z = {0.f, 0.f, 0.f, 0.f};
        ((float4*)(out + (size_t)(i0 + (tid >> 3)) * NROWS + j0))[tid & 7] = z;
        return;
    }

    __shared__ float hiL[32 * HST];
    __shared__ float hjL[32 * HST];

    const int lane = tid & 63;
    const int wid  = tid >> 6;
    const int col  = lane & 15;
    const int quad = lane >> 4;
    const int wj   = wid & 1;
    const int wi   = wid >> 1;

    // w2 A-frags (block-invariant): lane = channel ch_half*16+col, k = ks*32+quad*8+j
    Frag wf[2][2];
    #pragma unroll
    for (int ch = 0; ch < 2; ++ch)
        #pragma unroll
        for (int ks = 0; ks < 2; ++ks) {
            const float4* wr = (const float4*)(w2 + (ch * 16 + col) * 64 + ks * 32 + quad * 8);
            const float4 w0 = wr[0], w1v = wr[1];
            wf[ch][ks].u[0] = cvt2(w0.x, w0.y);
            wf[ch][ks].u[1] = cvt2(w0.z, w0.w);
            wf[ch][ks].u[2] = cvt2(w1v.x, w1v.y);
            wf[ch][ks].u[3] = cvt2(w1v.z, w1v.w);
        }
    // epilogue coefficients: lane's channels are quad*4+r (accA) / 16+quad*4+r (accB)
    const float4 b2A = *(const float4*)(b2 + quad * 4);
    const float4 b2B = *(const float4*)(b2 + 16 + quad * 4);
    const float4 w3A = *(const float4*)(w3 + quad * 4);
    const float4 w3B = *(const float4*)(w3 + 16 + quad * 4);
    const float b3v = b3[0];

    // stage hi/hj rows into LDS: 2048 floats each, 8 floats/thread
    {
        const int r = tid >> 3;
        const int c = (tid & 7) * 8;
        const float4* si = (const float4*)(hi_ws + (size_t)(i0 + r) * 64 + c);
        const float4* sj = (const float4*)(hj_ws + (size_t)(j0 + r) * 64 + c);
        const float4 a0 = si[0], a1 = si[1], b0 = sj[0], b1v = sj[1];
        *(float4*)&hiL[r * HST + c] = a0;
        *(float4*)&hiL[r * HST + c + 4] = a1;
        *(float4*)&hjL[r * HST + c] = b0;
        *(float4*)&hjL[r * HST + c + 4] = b1v;
    }
    __syncthreads();

    // loop-invariant hj fragment (this wave's 16 j's; lane's j = wj*16+col)
    const int hjbase = (wj * 16 + col) * HST + quad * 8;
    const float4 hj0 = *(const float4*)&hjL[hjbase];
    const float4 hj1 = *(const float4*)&hjL[hjbase + 4];
    const float4 hj2 = *(const float4*)&hjL[hjbase + 32];
    const float4 hj3 = *(const float4*)&hjL[hjbase + 36];

    const int jg = j0 + wj * 16 + col;

    for (int it = 0; it < 16; ++it) {
        const int il = wi * 16 + it;
        const int base = il * HST + quad * 8;
        // hi broadcast reads (same addr across the 16 lanes of a quad)
        const float4 x0 = *(const float4*)&hiL[base];
        const float4 x1 = *(const float4*)&hiL[base + 4];
        const float4 x2 = *(const float4*)&hiL[base + 32];
        const float4 x3 = *(const float4*)&hiL[base + 36];

        // h = relu(hi + hj) -> bf16 B-frags (lane: pair n=col, k=ks*32+quad*8+j)
        Frag f0, f1;
        f0.u[0] = cvt2(fmaxf(x0.x + hj0.x, 0.f), fmaxf(x0.y + hj0.y, 0.f));
        f0.u[1] = cvt2(fmaxf(x0.z + hj0.z, 0.f), fmaxf(x0.w + hj0.w, 0.f));
        f0.u[2] = cvt2(fmaxf(x1.x + hj1.x, 0.f), fmaxf(x1.y + hj1.y, 0.f));
        f0.u[3] = cvt2(fmaxf(x1.z + hj1.z, 0.f), fmaxf(x1.w + hj1.w, 0.f));
        f1.u[0] = cvt2(fmaxf(x2.x + hj2.x, 0.f), fmaxf(x2.y + hj2.y, 0.f));
        f1.u[1] = cvt2(fmaxf(x2.z + hj2.z, 0.f), fmaxf(x2.w + hj2.w, 0.f));
        f1.u[2] = cvt2(fmaxf(x3.x + hj3.x, 0.f), fmaxf(x3.y + hj3.y, 0.f));
        f1.u[3] = cvt2(fmaxf(x3.z + hj3.z, 0.f), fmaxf(x3.w + hj3.w, 0.f));

        f32x4 accA = {0.f, 0.f, 0.f, 0.f};
        f32x4 accB = {0.f, 0.f, 0.f, 0.f};
        accA = __builtin_amdgcn_mfma_f32_16x16x32_bf16(wf[0][0].v, f0.v, accA, 0, 0, 0);
        accA = __builtin_amdgcn_mfma_f32_16x16x32_bf16(wf[0][1].v, f1.v, accA, 0, 0, 0);
        accB = __builtin_amdgcn_mfma_f32_16x16x32_bf16(wf[1][0].v, f0.v, accB, 0, 0, 0);
        accB = __builtin_amdgcn_mfma_f32_16x16x32_bf16(wf[1][1].v, f1.v, accB, 0, 0, 0);

        // w3-dot over this lane's 8 channels (in-register)
        float p = w3A.x * fmaxf(accA[0] + b2A.x, 0.f)
                + w3A.y * fmaxf(accA[1] + b2A.y, 0.f)
                + w3A.z * fmaxf(accA[2] + b2A.z, 0.f)
                + w3A.w * fmaxf(accA[3] + b2A.w, 0.f)
                + w3B.x * fmaxf(accB[0] + b2B.x, 0.f)
                + w3B.y * fmaxf(accB[1] + b2B.y, 0.f)
                + w3B.z * fmaxf(accB[2] + b2B.z, 0.f)
                + w3B.w * fmaxf(accB[3] + b2B.w, 0.f);
        // reduce across the 4 quads (lanes xor 16, xor 32)
        p += __shfl_xor(p, 16, 64);
        p += __shfl_xor(p, 32, 64);

        if (quad == 0) {
            const int i = i0 + il;
            const float score = 1.f / (1.f + __expf(-(p + b3v)));
            out[(size_t)i * NROWS + jg] = (jg > i) ? score : 0.f;
        }
    }
}

extern "C" void kernel_launch(void* const* d_in, const int* in_sizes, int n_in,
                              void* d_out, int out_size, void* d_ws, size_t ws_size,
                              hipStream_t stream) {
    const int*   subj_idx   = (const int*)d_in[0];
    const int*   rel_idx    = (const int*)d_in[1];
    const int*   obj_idx    = (const int*)d_in[2];
    const float* subj_table = (const float*)d_in[3];
    const float* rel_table  = (const float*)d_in[4];
    const float* obj_table  = (const float*)d_in[5];
    const float* proj_w     = (const float*)d_in[6];
    const float* proj_b     = (const float*)d_in[7];
    const float* w1         = (const float*)d_in[8];
    const float* b1         = (const float*)d_in[9];
    const float* w2         = (const float*)d_in[10];
    const float* b2         = (const float*)d_in[11];
    const float* w3         = (const float*)d_in[12];
    const float* b3         = (const float*)d_in[13];
    float* out = (float*)d_out;

    float* hi_ws = (float*)d_ws;                 // N*64 floats
    float* hj_ws = hi_ws + NROWS * 64;           // N*64 floats

    precompute_kernel<<<dim3(NROWS / 4), dim3(256), 0, stream>>>(
        subj_idx, rel_idx, obj_idx, subj_table, rel_table, obj_table,
        proj_w, proj_b, w1, b1, hi_ws, hj_ws);

    pair_kernel<<<dim3(NROWS / 32, NROWS / 32), dim3(256), 0, stream>>>(
        hi_ws, hj_ws, w2, b2, w3, b3, out);
}